// Round 6
// baseline (517.226 us; speedup 1.0000x reference)
//
#include <hip/hip_runtime.h>
#include <stdint.h>

// LSTMModel via MFMA (f16 weights/h, fp32 acc/c): 2-layer LSTM (H1=50, H2=64),
// B=2048, T=512 + FC 64->32->16->1.
//
// Round 6: 512 blocks x 512 threads (8 waves), Nb=4 batch cols per block ->
// TWO independent blocks per CU (2 x 42KB LDS = 84KB < 160KB), so one block's
// barrier stalls hide under the other's issue. Wave wv owns M-tiles {2wv,2wv+1}
// (units 8wv+4tl+g). Skewed pipeline (layer2 one step behind), ONE barrier/step.
// All B-fragments shared across tiles (4 ds_read_b128/step). L2 chains seeded
// with bias via the MFMA C operand; L1 chains seeded with fma(w_ih1, x, bias).
// Quadrant redistribution (quad = nn>>2): q0: L1 tile0 (local); q1: L1 tile1
// (shfl_xor 4); q2: L2 tile0 (shfl_xor 8); q3: L2 tile1 (shfl_xor 12) ->
// exactly one unit-update per lane per step; activation col = nn&3.
// Invariant: h1(tau) in H1[(tau+1)&1], h2(tau) in H2[(tau+1)&1]; iter t reads
// h1(t-1)=H1[cur], h2(t-2)=H2[cur^1], writes h1(t)->H1[cur^1], h2(t-1)->H2[cur].
// t=0 forces c2=0. Pad units/tiles produce h=0 (zero A-rows, zero bias) so H
// rows 4..15 / units>=50 stay zero. Sigmoid/tanh via v_rcp_f32.

typedef _Float16 f16x8 __attribute__((ext_vector_type(8)));
typedef float f32x4 __attribute__((ext_vector_type(4)));

#define TLEN 512
#define STG 0            // 256x64 f16 staging = 32768 B (later: FC scratch)
#define H1OFF 32768      // 2 bufs x 16 rows x 144 B
#define H2OFF 37376
#define HSTR 144
#define HBUF 2304
#define LDSB 41984

__device__ __forceinline__ float rcpf_(float x) {
#if __has_builtin(__builtin_amdgcn_rcpf)
  return __builtin_amdgcn_rcpf(x);
#else
  return __fdividef(1.0f, x);
#endif
}
__device__ __forceinline__ float sigf(float z)   { return rcpf_(1.0f + __expf(-z)); }
__device__ __forceinline__ float tanhf_(float z) { return 1.0f - 2.0f * rcpf_(1.0f + __expf(2.0f * z)); }

#define MFMA16(A, B, C) __builtin_amdgcn_mfma_f32_16x16x32_f16(A, B, C, 0, 0, 0)

__global__ __launch_bounds__(512, 4)
void lstm_mfma(const float* __restrict__ x,
               const float* __restrict__ w_ih1, const float* __restrict__ w_hh1,
               const float* __restrict__ b_ih1, const float* __restrict__ b_hh1,
               const float* __restrict__ w_ih2, const float* __restrict__ w_hh2,
               const float* __restrict__ b_ih2, const float* __restrict__ b_hh2,
               const float* __restrict__ fc1_w, const float* __restrict__ fc1_b,
               const float* __restrict__ fc2_w, const float* __restrict__ fc2_b,
               const float* __restrict__ fc3_w, const float* __restrict__ fc3_b,
               float* __restrict__ out)
{
  __shared__ __align__(16) char smem[LDSB];
  const int tid = threadIdx.x;
  const int wv = tid >> 6, ln = tid & 63;
  const int nn = ln & 15, g = ln >> 4;
  const int quad = nn >> 2;               // 0: L1 t0, 1: L1 t1, 2: L2 t0, 3: L2 t1
  const bool isL2 = (quad >= 2);
  const int uA = wv * 8 + ((quad & 1) << 2) + g;   // this lane's assigned unit
  const int col = nn & 3;                          // this lane's assigned batch col

  _Float16* stg = (_Float16*)(smem + STG);
  f16x8 A1[2][2], A2i[2][2], A2h[2][2];

  // ---- stage + load A-fragments (gate-interleaved rows 4v+q, zero-padded) ----
  for (int idx = tid; idx < 16384; idx += 512) {
    int R = idx >> 6, k = idx & 63, v = R >> 2, q = R & 3;
    stg[idx] = (_Float16)((v < 50 && k < 50) ? w_hh1[(q * 50 + v) * 50 + k] : 0.f);
  }
  __syncthreads();
#pragma unroll
  for (int tl = 0; tl < 2; ++tl) {
    int base = ((wv * 2 + tl) * 16 + nn) * 128 + g * 16;
    A1[tl][0] = *(const f16x8*)(smem + STG + base);
    A1[tl][1] = *(const f16x8*)(smem + STG + base + 64);
  }
  __syncthreads();
  for (int idx = tid; idx < 16384; idx += 512) {
    int R = idx >> 6, k = idx & 63, v = R >> 2, q = R & 3;
    stg[idx] = (_Float16)((k < 50) ? w_ih2[(q * 64 + v) * 50 + k] : 0.f);
  }
  __syncthreads();
#pragma unroll
  for (int tl = 0; tl < 2; ++tl) {
    int base = ((wv * 2 + tl) * 16 + nn) * 128 + g * 16;
    A2i[tl][0] = *(const f16x8*)(smem + STG + base);
    A2i[tl][1] = *(const f16x8*)(smem + STG + base + 64);
  }
  __syncthreads();
  for (int idx = tid; idx < 16384; idx += 512) {
    int R = idx >> 6, k = idx & 63, v = R >> 2, q = R & 3;
    stg[idx] = (_Float16)(w_hh2[(q * 64 + v) * 64 + k]);
  }
  for (int i = tid; i < 2304; i += 512) ((uint32_t*)(smem + H1OFF))[i] = 0;  // zero H1+H2
  __syncthreads();
#pragma unroll
  for (int tl = 0; tl < 2; ++tl) {
    int base = ((wv * 2 + tl) * 16 + nn) * 128 + g * 16;
    A2h[tl][0] = *(const f16x8*)(smem + STG + base);
    A2h[tl][1] = *(const f16x8*)(smem + STG + base + 64);
  }
  __syncthreads();

  // ---- per-lane per-tile C-seeds: units u_tl = 8wv+4tl+g ----
  float w1c[2][4], b1c[2][4];
  f32x4 b2v[2];
#pragma unroll
  for (int tl = 0; tl < 2; ++tl) {
    int u = wv * 8 + tl * 4 + g;
#pragma unroll
    for (int q = 0; q < 4; ++q) {
      bool r1 = (u < 50);
      w1c[tl][q] = r1 ? w_ih1[q * 50 + u] : 0.f;
      b1c[tl][q] = r1 ? (b_ih1[q * 50 + u] + b_hh1[q * 50 + u]) : 0.f;
      b2v[tl][q] = b_ih2[q * 64 + u] + b_hh2[q * 64 + u];
    }
  }
  // L1 MFMA needed only for tiles m=2wv+tl <= 12
  const bool hasL1_0 = (wv <= 6), hasL1_1 = (wv <= 5);

  const float* xp = x + (blockIdx.x * 4 + col) * TLEN;

  // write pointers: L1 lanes -> H1[nxt] row col, unit uA; L2 -> H2[cur] row col
  _Float16 *wp0, *wp1;  // for cur=0 / cur=1
  if (!isL2) {
    wp0 = (_Float16*)(smem + H1OFF + HBUF + col * HSTR + uA * 2);
    wp1 = (_Float16*)(smem + H1OFF +    0 + col * HSTR + uA * 2);
  } else {
    wp0 = (_Float16*)(smem + H2OFF +    0 + col * HSTR + uA * 2);
    wp1 = (_Float16*)(smem + H2OFF + HBUF + col * HSTR + uA * 2);
  }

  const char* const h1b = smem + H1OFF + nn * HSTR;
  const char* const h2b = smem + H2OFF + nn * HSTR;

  float cs = 0.f;   // this lane's c-state (c1 or c2 per duty)

  for (int tb = 0; tb < TLEN; tb += 8) {
    const float4 xa = *(const float4*)&xp[tb];
    const float4 xb = *(const float4*)&xp[tb + 4];
    const float x8[8] = {xa.x, xa.y, xa.z, xa.w, xb.x, xb.y, xb.z, xb.w};
#pragma unroll
    for (int k = 0; k < 8; ++k) {
      const int cur = k & 1;
      const bool first = (tb == 0) && (k == 0);

      const f16x8 b0 = *(const f16x8*)(h1b + cur * HBUF + g * 16);
      const f16x8 b1 = *(const f16x8*)(h1b + cur * HBUF + 64 + g * 16);
      const f16x8 q0 = *(const f16x8*)(h2b + (cur ^ 1) * HBUF + g * 16);
      const f16x8 q1 = *(const f16x8*)(h2b + (cur ^ 1) * HBUF + 64 + g * 16);

      // layer-2 chains, both tiles, C seeded with bias
      f32x4 d0 = MFMA16(A2i[0][0], b0, b2v[0]);
      d0 = MFMA16(A2i[0][1], b1, d0);
      d0 = MFMA16(A2h[0][0], q0, d0);
      d0 = MFMA16(A2h[0][1], q1, d0);
      f32x4 d1 = MFMA16(A2i[1][0], b0, b2v[1]);
      d1 = MFMA16(A2i[1][1], b1, d1);
      d1 = MFMA16(A2h[1][0], q0, d1);
      d1 = MFMA16(A2h[1][1], q1, d1);

      // layer-1 chains (real tiles only), C seeded with w_ih1*x + bias
      const float xv = x8[k];
      f32x4 acc0, acc1;
      acc0[0] = fmaf(w1c[0][0], xv, b1c[0][0]);
      acc0[1] = fmaf(w1c[0][1], xv, b1c[0][1]);
      acc0[2] = fmaf(w1c[0][2], xv, b1c[0][2]);
      acc0[3] = fmaf(w1c[0][3], xv, b1c[0][3]);
      acc1[0] = fmaf(w1c[1][0], xv, b1c[1][0]);
      acc1[1] = fmaf(w1c[1][1], xv, b1c[1][1]);
      acc1[2] = fmaf(w1c[1][2], xv, b1c[1][2]);
      acc1[3] = fmaf(w1c[1][3], xv, b1c[1][3]);
      if (hasL1_0) {
        acc0 = MFMA16(A1[0][0], b0, acc0);
        acc0 = MFMA16(A1[0][1], b1, acc0);
      }
      if (hasL1_1) {
        acc1 = MFMA16(A1[1][0], b0, acc1);
        acc1 = MFMA16(A1[1][1], b1, acc1);
      }

      // quadrant redistribution: one unit-update per lane
      float z0, z1, z2, z3;
      {
        const float a10 = __shfl_xor(acc1[0], 4, 64), a11 = __shfl_xor(acc1[1], 4, 64);
        const float a12 = __shfl_xor(acc1[2], 4, 64), a13 = __shfl_xor(acc1[3], 4, 64);
        const float d00 = __shfl_xor(d0[0], 8, 64),  d01 = __shfl_xor(d0[1], 8, 64);
        const float d02 = __shfl_xor(d0[2], 8, 64),  d03 = __shfl_xor(d0[3], 8, 64);
        const float d10 = __shfl_xor(d1[0], 12, 64), d11 = __shfl_xor(d1[1], 12, 64);
        const float d12 = __shfl_xor(d1[2], 12, 64), d13 = __shfl_xor(d1[3], 12, 64);
        const float l0 = (quad & 1) ? a10 : acc0[0], m0 = (quad & 1) ? d10 : d00;
        const float l1 = (quad & 1) ? a11 : acc0[1], m1 = (quad & 1) ? d11 : d01;
        const float l2 = (quad & 1) ? a12 : acc0[2], m2 = (quad & 1) ? d12 : d02;
        const float l3 = (quad & 1) ? a13 : acc0[3], m3 = (quad & 1) ? d13 : d03;
        z0 = isL2 ? m0 : l0;  z1 = isL2 ? m1 : l1;
        z2 = isL2 ? m2 : l2;  z3 = isL2 ? m3 : l3;
      }

      // unit update: i,f,g,o -> c,h
      const float gi = sigf(z0), gf = sigf(z1), gg = tanhf_(z2), go = sigf(z3);
      float c = gf * cs + gi * gg;
      if (first && isL2) c = 0.f;     // h2(-1)=0
      cs = c;
      const float h = go * tanhf_(c);
      *(cur ? wp1 : wp0) = (_Float16)h;
      __syncthreads();   // the ONE barrier per step
    }
  }

  // ---- epilogue: h2(511) from h1(511)=H1[0], h2(510)=H2[1] ----
  {
    const f16x8 b0 = *(const f16x8*)(h1b + g * 16);
    const f16x8 b1 = *(const f16x8*)(h1b + 64 + g * 16);
    const f16x8 q0 = *(const f16x8*)(h2b + HBUF + g * 16);
    const f16x8 q1 = *(const f16x8*)(h2b + HBUF + 64 + g * 16);
    f32x4 d0 = MFMA16(A2i[0][0], b0, b2v[0]);
    d0 = MFMA16(A2i[0][1], b1, d0);
    d0 = MFMA16(A2h[0][0], q0, d0);
    d0 = MFMA16(A2h[0][1], q1, d0);
    f32x4 d1 = MFMA16(A2i[1][0], b0, b2v[1]);
    d1 = MFMA16(A2i[1][1], b1, d1);
    d1 = MFMA16(A2h[1][0], q0, d1);
    d1 = MFMA16(A2h[1][1], q1, d1);
    const float d00 = __shfl_xor(d0[0], 8, 64),  d01 = __shfl_xor(d0[1], 8, 64);
    const float d02 = __shfl_xor(d0[2], 8, 64),  d03 = __shfl_xor(d0[3], 8, 64);
    const float d10 = __shfl_xor(d1[0], 12, 64), d11 = __shfl_xor(d1[1], 12, 64);
    const float d12 = __shfl_xor(d1[2], 12, 64), d13 = __shfl_xor(d1[3], 12, 64);
    __syncthreads();   // all reads of H bufs done; smem base reusable
    if (isL2) {
      const float z0 = (quad & 1) ? d10 : d00, z1 = (quad & 1) ? d11 : d01;
      const float z2 = (quad & 1) ? d12 : d02, z3 = (quad & 1) ? d13 : d03;
      const float gi = sigf(z0), gf = sigf(z1), gg = tanhf_(z2), go = sigf(z3);
      const float c = gf * cs + gi * gg;
      const float h = go * tanhf_(c);
      ((float*)smem)[col * 64 + uA] = h;   // fp32 h2(511): [4][64]
    }
  }
  __syncthreads();

  // ---- FC head: 64 -> 32 -> 16 -> 1 (4 batch rows) ----
  float* h2f = (float*)smem;                 // [4][64]
  float* f1o = (float*)(smem + 4096);        // [4][32]
  float* f2o = (float*)(smem + 4096 + 1024); // [4][16]
  if (tid < 128) {
    int o = tid & 31, n = tid >> 5;
    float s = fc1_b[o];
#pragma unroll 8
    for (int k = 0; k < 64; ++k) s = fmaf(h2f[n * 64 + k], fc1_w[o * 64 + k], s);
    f1o[n * 32 + o] = s;
  }
  __syncthreads();
  if (tid < 64) {
    int o = tid & 15, n = tid >> 4;
    float s = fc2_b[o];
#pragma unroll 8
    for (int k = 0; k < 32; ++k) s = fmaf(f1o[n * 32 + k], fc2_w[o * 32 + k], s);
    f2o[n * 16 + o] = s;
  }
  __syncthreads();
  if (tid < 4) {
    float s = fc3_b[0];
#pragma unroll
    for (int k = 0; k < 16; ++k) s = fmaf(f2o[tid * 16 + k], fc3_w[k], s);
    out[blockIdx.x * 4 + tid] = s;
  }
}

extern "C" void kernel_launch(void* const* d_in, const int* in_sizes, int n_in,
                              void* d_out, int out_size, void* d_ws, size_t ws_size,
                              hipStream_t stream) {
  const float* x     = (const float*)d_in[0];
  const float* w_ih1 = (const float*)d_in[1];
  const float* w_hh1 = (const float*)d_in[2];
  const float* b_ih1 = (const float*)d_in[3];
  const float* b_hh1 = (const float*)d_in[4];
  const float* w_ih2 = (const float*)d_in[5];
  const float* w_hh2 = (const float*)d_in[6];
  const float* b_ih2 = (const float*)d_in[7];
  const float* b_hh2 = (const float*)d_in[8];
  const float* fc1_w = (const float*)d_in[9];
  const float* fc1_b = (const float*)d_in[10];
  const float* fc2_w = (const float*)d_in[11];
  const float* fc2_b = (const float*)d_in[12];
  const float* fc3_w = (const float*)d_in[13];
  const float* fc3_b = (const float*)d_in[14];

  hipLaunchKernelGGL(lstm_mfma, dim3(512), dim3(512), 0, stream,
                     x, w_ih1, w_hh1, b_ih1, b_hh1,
                     w_ih2, w_hh2, b_ih2, b_hh2,
                     fc1_w, fc1_b, fc2_w, fc2_b, fc3_w, fc3_b,
                     (float*)d_out);
}

// Round 7
// 351.836 us; speedup vs baseline: 1.4701x; 1.4701x over previous
//
#include <hip/hip_runtime.h>
#include <stdint.h>

// LSTMModel via MFMA (f16 weights/h, fp32 acc/c): 2-layer LSTM (H1=50, H2=64),
// B=2048, T=512 + FC 64->32->16->1.
//
// Round 7 = Round 5 structure (256 blocks x 1024 threads, 16 waves, Nb=8,
// skewed pipeline, ONE barrier/step) + critical-path fixes:
//  - __shfl_xor(d,8) + select  ->  ONE v_mov_b32_dpp update (row_ror:8,
//    bank_mask 0xC): lanes nn<8 keep acc (layer-1 z), lanes nn>=8 receive d
//    from lane^8 (layer-2 z). VALU op, off the LDS pipe, no lgkm wait.
//  - x loaded one 8-step block AHEAD (float4 pair double-buffer), so the
//    global-load latency never sits inside a barrier interval.
// R6 lesson: Nb=4/block (2 blocks/CU) doubles per-batch MFMA work - never
// shrink N-fill below 8 to buy co-residency.
// Invariant: h1(tau) in H1[(tau+1)&1], h2(tau) in H2[(tau+1)&1]. At iter t
// (cur=t&1): read h1(t-1)=H1[cur], h2(t-2)=H2[cur^1]; write h1(t)->H1[cur^1]
// (lanes nn<8), h2(t-1)->H2[cur] (lanes nn>=8). t=0 forces c2=0 (h2(-1)=0).

typedef _Float16 f16x8 __attribute__((ext_vector_type(8)));
typedef float f32x4 __attribute__((ext_vector_type(4)));

#define TLEN 512
#define STG 0            // 256x64 f16 staging = 32768 B (later: FC scratch)
#define H1OFF 32768      // 2 bufs x 16 rows x 144 B
#define H2OFF 37376
#define HSTR 144
#define HBUF 2304
#define LDSB 41984

__device__ __forceinline__ float rcpf_(float x) {
#if __has_builtin(__builtin_amdgcn_rcpf)
  return __builtin_amdgcn_rcpf(x);
#else
  return __fdividef(1.0f, x);
#endif
}
__device__ __forceinline__ float sigf(float z)   { return rcpf_(1.0f + __expf(-z)); }
__device__ __forceinline__ float tanhf_(float z) { return 1.0f - 2.0f * rcpf_(1.0f + __expf(2.0f * z)); }

// lanes in banks 2,3 of each 16-lane DPP row (nn>=8) get dv from lane^8;
// lanes nn<8 keep av. row_ror:8 == xor-8 within a 16-lane row.
__device__ __forceinline__ float dppsel(float av, float dv) {
  return __int_as_float(__builtin_amdgcn_update_dpp(
      __float_as_int(av), __float_as_int(dv),
      0x128 /*row_ror:8*/, 0xF /*row_mask*/, 0xC /*bank_mask: banks 2,3*/, false));
}

#define MFMA16(A, B, C) __builtin_amdgcn_mfma_f32_16x16x32_f16(A, B, C, 0, 0, 0)

__global__ __launch_bounds__(1024, 1)
void lstm_mfma(const float* __restrict__ x,
               const float* __restrict__ w_ih1, const float* __restrict__ w_hh1,
               const float* __restrict__ b_ih1, const float* __restrict__ b_hh1,
               const float* __restrict__ w_ih2, const float* __restrict__ w_hh2,
               const float* __restrict__ b_ih2, const float* __restrict__ b_hh2,
               const float* __restrict__ fc1_w, const float* __restrict__ fc1_b,
               const float* __restrict__ fc2_w, const float* __restrict__ fc2_b,
               const float* __restrict__ fc3_w, const float* __restrict__ fc3_b,
               float* __restrict__ out)
{
  __shared__ __align__(16) char smem[LDSB];
  const int tid = threadIdx.x;
  const int wv = tid >> 6, ln = tid & 63;
  const int nn = ln & 15, g = ln >> 4;
  const int u = wv * 4 + g;               // this lane's unit (both layers)
  const bool isUpper = (nn >= 8);         // upper half-cols: layer-2 duty
  const bool hasL1 = (wv <= 12);          // waves 13..15: layer-1 tile is all zero

  _Float16* stg = (_Float16*)(smem + STG);
  f16x8 A1[2], A2i[2], A2h[2];

  // ---- stage + load A-fragments (gate-interleaved rows 4v+q, zero-padded) ----
  for (int idx = tid; idx < 16384; idx += 1024) {
    int R = idx >> 6, k = idx & 63, v = R >> 2, q = R & 3;
    stg[idx] = (_Float16)((v < 50 && k < 50) ? w_hh1[(q * 50 + v) * 50 + k] : 0.f);
  }
  __syncthreads();
  {
    int base = (wv * 16 + nn) * 128 + g * 16;
    A1[0] = *(const f16x8*)(smem + STG + base);
    A1[1] = *(const f16x8*)(smem + STG + base + 64);
  }
  __syncthreads();
  for (int idx = tid; idx < 16384; idx += 1024) {
    int R = idx >> 6, k = idx & 63, v = R >> 2, q = R & 3;
    stg[idx] = (_Float16)((k < 50) ? w_ih2[(q * 64 + v) * 50 + k] : 0.f);
  }
  __syncthreads();
  {
    int base = (wv * 16 + nn) * 128 + g * 16;
    A2i[0] = *(const f16x8*)(smem + STG + base);
    A2i[1] = *(const f16x8*)(smem + STG + base + 64);
  }
  __syncthreads();
  for (int idx = tid; idx < 16384; idx += 1024) {
    int R = idx >> 6, k = idx & 63, v = R >> 2, q = R & 3;
    stg[idx] = (_Float16)(w_hh2[(q * 64 + v) * 64 + k]);
  }
  for (int i = tid; i < 2304; i += 1024) ((uint32_t*)(smem + H1OFF))[i] = 0;  // zero H1+H2
  __syncthreads();
  {
    int base = (wv * 16 + nn) * 128 + g * 16;
    A2h[0] = *(const f16x8*)(smem + STG + base);
    A2h[1] = *(const f16x8*)(smem + STG + base + 64);
  }
  __syncthreads();

  // ---- per-lane constants for unit u ----
  float w1c[4], b1c[4];
  f32x4 b2v;
#pragma unroll
  for (int q = 0; q < 4; ++q) {
    bool r1 = (u < 50);
    w1c[q] = r1 ? w_ih1[q * 50 + u] : 0.f;
    b1c[q] = r1 ? (b_ih1[q * 50 + u] + b_hh1[q * 50 + u]) : 0.f;
    b2v[q] = b_ih2[q * 64 + u] + b_hh2[q * 64 + u];
  }

  const float* xp = x + (blockIdx.x * 8 + (nn & 7)) * TLEN;

  // write pointers for cur=0 / cur=1 (lower: h1(t)->H1[cur^1]; upper: h2(t-1)->H2[cur])
  _Float16 *wp0, *wp1;
  if (!isUpper) {
    wp0 = (_Float16*)(smem + H1OFF + HBUF + nn * HSTR + u * 2);
    wp1 = (_Float16*)(smem + H1OFF +    0 + nn * HSTR + u * 2);
  } else {
    wp0 = (_Float16*)(smem + H2OFF +    0 + (nn - 8) * HSTR + u * 2);
    wp1 = (_Float16*)(smem + H2OFF + HBUF + (nn - 8) * HSTR + u * 2);
  }
  const bool doWrite = isUpper || hasL1;

  const char* const h1b = smem + H1OFF + nn * HSTR;
  const char* const h2b = smem + H2OFF + nn * HSTR;

  float cs = 0.f;                       // c1 (lower lanes) or c2 (upper lanes)
  f32x4 acc = {0.f, 0.f, 0.f, 0.f};     // layer-1 z (stays 0 for waves 13..15)

  // x double-buffer: current 8 steps in (xa,xb), next 8 prefetched into (na,nb)
  float4 xa = *(const float4*)&xp[0];
  float4 xb = *(const float4*)&xp[4];

  for (int tb = 0; tb < TLEN; tb += 8) {
    float4 na = {0.f, 0.f, 0.f, 0.f}, nb = {0.f, 0.f, 0.f, 0.f};
    if (tb + 8 < TLEN) {
      na = *(const float4*)&xp[tb + 8];
      nb = *(const float4*)&xp[tb + 12];
    }
    const float x8[8] = {xa.x, xa.y, xa.z, xa.w, xb.x, xb.y, xb.z, xb.w};
#pragma unroll
    for (int k = 0; k < 8; ++k) {
      const int cur = k & 1;
      const bool first = (tb == 0) && (k == 0);

      const f16x8 b0 = *(const f16x8*)(h1b + cur * HBUF + g * 16);
      const f16x8 b1 = *(const f16x8*)(h1b + cur * HBUF + 64 + g * 16);
      const f16x8 q0 = *(const f16x8*)(h2b + (cur ^ 1) * HBUF + g * 16);
      const f16x8 q1 = *(const f16x8*)(h2b + (cur ^ 1) * HBUF + 64 + g * 16);

      // layer-2 chain (all lanes), C seeded with bias
      f32x4 d = MFMA16(A2i[0], b0, b2v);
      d = MFMA16(A2i[1], b1, d);
      d = MFMA16(A2h[0], q0, d);
      d = MFMA16(A2h[1], q1, d);

      // layer-1 chain (waves 0..12), C seeded with w_ih1*x + bias
      if (hasL1) {
        const float xv = x8[k];
        f32x4 s;
        s[0] = fmaf(w1c[0], xv, b1c[0]);
        s[1] = fmaf(w1c[1], xv, b1c[1]);
        s[2] = fmaf(w1c[2], xv, b1c[2]);
        s[3] = fmaf(w1c[3], xv, b1c[3]);
        acc = MFMA16(A1[0], b0, s);
        acc = MFMA16(A1[1], b1, acc);
      }

      // fused permute+select: lower lanes keep acc (L1 z), upper get d from lane^8
      const float z0 = dppsel(acc[0], d[0]);
      const float z1 = dppsel(acc[1], d[1]);
      const float z2 = dppsel(acc[2], d[2]);
      const float z3 = dppsel(acc[3], d[3]);

      // one unit-update per lane: i,f,g,o -> c,h
      const float gi = sigf(z0), gf = sigf(z1), gg = tanhf_(z2), go = sigf(z3);
      float c = gf * cs + gi * gg;
      if (first) { if (isUpper) c = 0.f; }   // h2(-1)=0
      cs = c;
      const float h = go * tanhf_(c);
      if (doWrite) *(cur ? wp1 : wp0) = (_Float16)h;
      __syncthreads();   // the ONE barrier per step
    }
    xa = na; xb = nb;
  }

  // ---- epilogue: h2(511) from h1(511)=H1[0], h2(510)=H2[1] ----
  {
    const f16x8 b0 = *(const f16x8*)(h1b + g * 16);
    const f16x8 b1 = *(const f16x8*)(h1b + 64 + g * 16);
    const f16x8 q0 = *(const f16x8*)(h2b + HBUF + g * 16);
    const f16x8 q1 = *(const f16x8*)(h2b + HBUF + 64 + g * 16);
    f32x4 d = MFMA16(A2i[0], b0, b2v);
    d = MFMA16(A2i[1], b1, d);
    d = MFMA16(A2h[0], q0, d);
    d = MFMA16(A2h[1], q1, d);
    const float dr0 = dppsel(0.f, d[0]);
    const float dr1 = dppsel(0.f, d[1]);
    const float dr2 = dppsel(0.f, d[2]);
    const float dr3 = dppsel(0.f, d[3]);
    if (isUpper) {
      const float gi = sigf(dr0), gf = sigf(dr1), gg = tanhf_(dr2), go = sigf(dr3);
      const float c = gf * cs + gi * gg;
      const float h = go * tanhf_(c);
      ((float*)smem)[(nn - 8) * 64 + u] = h;   // fp32 h2(511): [8][64]
    }
  }
  __syncthreads();

  // ---- FC head: 64 -> 32 -> 16 -> 1 ----
  float* h2f = (float*)smem;                 // [8][64]
  float* f1o = (float*)(smem + 4096);        // [8][32]
  float* f2o = (float*)(smem + 4096 + 1024); // [8][16]
  if (tid < 256) {
    int o = tid & 31, n = tid >> 5;
    float s = fc1_b[o];
#pragma unroll 8
    for (int k = 0; k < 64; ++k) s = fmaf(h2f[n * 64 + k], fc1_w[o * 64 + k], s);
    f1o[n * 32 + o] = s;
  }
  __syncthreads();
  if (tid < 128) {
    int o = tid & 15, n = tid >> 4;
    float s = fc2_b[o];
#pragma unroll 8
    for (int k = 0; k < 32; ++k) s = fmaf(f1o[n * 32 + k], fc2_w[o * 32 + k], s);
    f2o[n * 16 + o] = s;
  }
  __syncthreads();
  if (tid < 8) {
    float s = fc3_b[0];
#pragma unroll
    for (int k = 0; k < 16; ++k) s = fmaf(f2o[tid * 16 + k], fc3_w[k], s);
    out[blockIdx.x * 8 + tid] = s;
  }
}

extern "C" void kernel_launch(void* const* d_in, const int* in_sizes, int n_in,
                              void* d_out, int out_size, void* d_ws, size_t ws_size,
                              hipStream_t stream) {
  const float* x     = (const float*)d_in[0];
  const float* w_ih1 = (const float*)d_in[1];
  const float* w_hh1 = (const float*)d_in[2];
  const float* b_ih1 = (const float*)d_in[3];
  const float* b_hh1 = (const float*)d_in[4];
  const float* w_ih2 = (const float*)d_in[5];
  const float* w_hh2 = (const float*)d_in[6];
  const float* b_ih2 = (const float*)d_in[7];
  const float* b_hh2 = (const float*)d_in[8];
  const float* fc1_w = (const float*)d_in[9];
  const float* fc1_b = (const float*)d_in[10];
  const float* fc2_w = (const float*)d_in[11];
  const float* fc2_b = (const float*)d_in[12];
  const float* fc3_w = (const float*)d_in[13];
  const float* fc3_b = (const float*)d_in[14];

  hipLaunchKernelGGL(lstm_mfma, dim3(256), dim3(1024), 0, stream,
                     x, w_ih1, w_hh1, b_ih1, b_hh1,
                     w_ih2, w_hh2, b_ih2, b_hh2,
                     fc1_w, fc1_b, fc2_w, fc2_b, fc3_w, fc3_b,
                     (float*)d_out);
}